// Round 1
// baseline (660.605 us; speedup 1.0000x reference)
//
#include <hip/hip_runtime.h>
#include <hip/hip_bf16.h>

#define NB 512
#define KD 128
#define VD 64
#define NKEYS 500000
#define TOPK 16
#define CH 1024
#define NCHUNK 489            // ceil(500000/1024)
#define NCAND (NCHUNK*4)

typedef __attribute__((ext_vector_type(8))) short bf8s;
typedef __attribute__((ext_vector_type(4))) float f4;

__device__ __forceinline__ unsigned f2bf(float x) {
  union { float f; unsigned u; } v; v.f = x;
  return (v.u + 0x7fffu + ((v.u >> 16) & 1u)) >> 16;   // RNE fp32->bf16
}

// ---------------- Kernel 1: normalize queries, fold in 1/temperature = 4 ----
__global__ __launch_bounds__(128) void qnorm_kernel(const float* __restrict__ q,
                                                    float* __restrict__ qn_f,
                                                    short* __restrict__ qn_bf) {
  int b = blockIdx.x, t = threadIdx.x;
  float x = q[b*KD + t];
  float s = x * x;
  #pragma unroll
  for (int o = 32; o > 0; o >>= 1) s += __shfl_down(s, o);
  __shared__ float p[2];
  if ((t & 63) == 0) p[t >> 6] = s;
  __syncthreads();
  float norm = sqrtf(p[0] + p[1]);
  norm = fmaxf(norm, 1e-8f);
  float v = x * (4.0f / norm);        // qn * (1/0.25); *4 is exact in fp32
  qn_f[b*KD + t] = v;
  qn_bf[b*KD + t] = (short)f2bf(v);
}

// ---------------- Kernel 2: bf16 MFMA approx scores + per-chunk local top-4 --
// grid = (NCHUNK, 2). Block: 256 threads = 4 waves; each wave owns 64 queries
// (4 MFMA m-tiles), all waves share the same 16-key n-tile per pass.
__global__ __launch_bounds__(256) void score_filter_kernel(
    const float* __restrict__ keys, const short* __restrict__ qn_bf,
    float* __restrict__ cand_val, int* __restrict__ cand_idx) {
  __shared__ float slds[256 * 17];           // [256 queries][16 cols], pad 17
  const int chunk = blockIdx.x, gy = blockIdx.y;
  const int tid  = threadIdx.x;
  const int wave = tid >> 6, lane = tid & 63;
  const int col  = lane & 15, quad = lane >> 4;

  // A fragments: A[m = lane&15][k = quad*8 + j], held in regs for whole chunk
  bf8s afrag[4][4];
  const int qbase = gy*256 + wave*64;
  #pragma unroll
  for (int mt = 0; mt < 4; mt++)
    #pragma unroll
    for (int ks = 0; ks < 4; ks++)
      afrag[mt][ks] = *(const bf8s*)(qn_bf + (qbase + mt*16 + col)*KD + ks*32 + quad*8);

  float tv0=-1e30f, tv1=-1e30f, tv2=-1e30f, tv3=-1e30f;
  int   ti0=0, ti1=0, ti2=0, ti3=0;
  const int nchunk0 = chunk * CH;

  for (int nt = 0; nt < CH/16; nt++) {
    const int nb = nchunk0 + nt*16;
    int r = nb + col; if (r > NKEYS-1) r = NKEYS-1;        // clamp OOB rows
    const float* kp = keys + (size_t)r*KD + quad*8;
    // B fragments: B[k = quad*8 + j][n = lane&15], fp32 -> bf16 in regs
    bf8s bfrag[4];
    #pragma unroll
    for (int ks = 0; ks < 4; ks++) {
      f4 x0 = *(const f4*)(kp + ks*32);
      f4 x1 = *(const f4*)(kp + ks*32 + 4);
      bf8s tt;
      tt[0]=(short)f2bf(x0[0]); tt[1]=(short)f2bf(x0[1]);
      tt[2]=(short)f2bf(x0[2]); tt[3]=(short)f2bf(x0[3]);
      tt[4]=(short)f2bf(x1[0]); tt[5]=(short)f2bf(x1[1]);
      tt[6]=(short)f2bf(x1[2]); tt[7]=(short)f2bf(x1[3]);
      bfrag[ks] = tt;
    }
    f4 acc[4];
    #pragma unroll
    for (int mt = 0; mt < 4; mt++) { acc[mt][0]=0.f; acc[mt][1]=0.f; acc[mt][2]=0.f; acc[mt][3]=0.f; }
    #pragma unroll
    for (int ks = 0; ks < 4; ks++)
      #pragma unroll
      for (int mt = 0; mt < 4; mt++)
        acc[mt] = __builtin_amdgcn_mfma_f32_16x16x32_bf16(afrag[mt][ks], bfrag[ks], acc[mt], 0, 0, 0);
    // C/D layout: col = lane&15, row = quad*4 + reg  (m89-verified)
    #pragma unroll
    for (int mt = 0; mt < 4; mt++)
      #pragma unroll
      for (int rg = 0; rg < 4; rg++)
        slds[(wave*64 + mt*16 + quad*4 + rg)*17 + col] = acc[mt][rg];
    __syncthreads();
    // selection: thread t owns query (gy*256 + t); scan 16 cols
    #pragma unroll
    for (int c = 0; c < 16; c++) {
      int n = nb + c;
      float v = slds[tid*17 + c];
      if (v > tv3 && n < NKEYS) {
        if (v > tv0)      { tv3=tv2;ti3=ti2; tv2=tv1;ti2=ti1; tv1=tv0;ti1=ti0; tv0=v;ti0=n; }
        else if (v > tv1) { tv3=tv2;ti3=ti2; tv2=tv1;ti2=ti1; tv1=v;ti1=n; }
        else if (v > tv2) { tv3=tv2;ti3=ti2; tv2=v;ti2=n; }
        else              { tv3=v;ti3=n; }
      }
    }
    __syncthreads();
  }
  const int gq = gy*256 + tid;
  const size_t o = ((size_t)gq*NCHUNK + chunk)*4;
  cand_val[o+0]=tv0; cand_val[o+1]=tv1; cand_val[o+2]=tv2; cand_val[o+3]=tv3;
  cand_idx[o+0]=ti0; cand_idx[o+1]=ti1; cand_idx[o+2]=ti2; cand_idx[o+3]=ti3;
}

// ---------------- Kernel 3: merge -> approx top-32 -> exact fp32 rescore ----
__global__ __launch_bounds__(256) void merge_rescore_kernel(
    const float* __restrict__ qn_f, const float* __restrict__ keys,
    const float* __restrict__ values, const float* __restrict__ cand_val,
    const int* __restrict__ cand_idx, float* __restrict__ out) {
  const int b = blockIdx.x, t = threadIdx.x;
  const int lane = t & 63, wave = t >> 6;
  __shared__ float cv[NCAND]; __shared__ int ci[NCAND];
  __shared__ float qs[KD];
  __shared__ float redv[4]; __shared__ int redp[4];
  __shared__ float rv[32];  __shared__ int ri[32];
  __shared__ float sval[16]; __shared__ int sidx[16]; __shared__ float sw[16];

  if (t < KD) qs[t] = qn_f[b*KD + t];
  for (int i = t; i < NCAND; i += 256) {
    cv[i] = cand_val[(size_t)b*NCAND + i];
    ci[i] = cand_idx[(size_t)b*NCAND + i];
  }
  __syncthreads();

  // 32 rounds of block-wide argmax (approx top-32; ordering here irrelevant)
  for (int rdx = 0; rdx < 32; rdx++) {
    float mv = -1e30f; int mp = 0;
    for (int i = t; i < NCAND; i += 256) { float v = cv[i]; if (v > mv) { mv = v; mp = i; } }
    #pragma unroll
    for (int o = 32; o > 0; o >>= 1) {
      float ov = __shfl_down(mv, o); int op = __shfl_down(mp, o);
      if (ov > mv) { mv = ov; mp = op; }
    }
    if (lane == 0) { redv[wave] = mv; redp[wave] = mp; }
    __syncthreads();
    if (t == 0) {
      float bv = redv[0]; int bp = redp[0];
      for (int w = 1; w < 4; w++) if (redv[w] > bv) { bv = redv[w]; bp = redp[w]; }
      ri[rdx] = ci[bp];
      cv[bp] = -1e30f;
    }
    __syncthreads();
  }

  // exact fp32 rescore of the 32 candidates: 8 threads x 16 dims each
  {
    int c = t >> 3, dg = t & 7;
    int n = ri[c];
    const float* kr = keys + (size_t)n*KD + dg*16;
    float part = 0.f;
    #pragma unroll
    for (int j = 0; j < 16; j++) part += kr[j] * qs[dg*16 + j];
    #pragma unroll
    for (int o = 4; o > 0; o >>= 1) part += __shfl_down(part, o, 8);
    if (dg == 0) rv[c] = part;
  }
  __syncthreads();

  // exact rank (desc value, tie -> lower index, matching jax.lax.top_k)
  if (t < 32) {
    float v = rv[t]; int idx = ri[t];
    int rank = 0;
    for (int j = 0; j < 32; j++) {
      float vj = rv[j]; int ij = ri[j];
      rank += (vj > v) || (vj == v && ij < idx);
    }
    if (rank < TOPK) { sval[rank] = v; sidx[rank] = idx; }
  }
  __syncthreads();

  // softmax with +eps denominator; write topw and topidx (as float)
  if (t < TOPK) {
    float m = sval[0];
    float e = expf(sval[t] - m);
    float s = e;
    #pragma unroll
    for (int o = 8; o > 0; o >>= 1) s += __shfl_down(s, o, 16);
    s = __shfl(s, 0, 16);
    float w = e / (s + 1e-8f);
    sw[t] = w;
    out[NB*VD + b*TOPK + t] = w;                       // topw
    out[NB*VD + NB*TOPK + b*TOPK + t] = (float)sidx[t]; // topidx as float
  }
  __syncthreads();

  // retrieved = sum_k w_k * values[idx_k]
  if (t < VD) {
    float acc = 0.f;
    #pragma unroll
    for (int k = 0; k < TOPK; k++) acc += sw[k] * values[(size_t)sidx[k]*VD + t];
    out[b*VD + t] = acc;
  }
}

extern "C" void kernel_launch(void* const* d_in, const int* in_sizes, int n_in,
                              void* d_out, int out_size, void* d_ws, size_t ws_size,
                              hipStream_t stream) {
  const float* queries = (const float*)d_in[0];
  const float* keys    = (const float*)d_in[1];
  const float* values  = (const float*)d_in[2];
  float* out = (float*)d_out;

  char* ws = (char*)d_ws;
  float* qn_f  = (float*)ws;                                   // 512*128 f32
  short* qn_bf = (short*)(ws + (size_t)NB*KD*4);               // 512*128 bf16
  float* cand_val = (float*)(ws + (size_t)NB*KD*4 + (size_t)NB*KD*2);
  int*   cand_idx = (int*)((char*)cand_val + (size_t)NB*NCHUNK*4*sizeof(float));

  qnorm_kernel<<<NB, KD, 0, stream>>>(queries, qn_f, qn_bf);
  score_filter_kernel<<<dim3(NCHUNK, 2), 256, 0, stream>>>(keys, qn_bf, cand_val, cand_idx);
  merge_rescore_kernel<<<NB, 256, 0, stream>>>(qn_f, keys, values, cand_val, cand_idx, out);
}